// Round 13
// baseline (371.126 us; speedup 1.0000x reference)
//
#include <hip/hip_runtime.h>
#include <hip/hip_bf16.h>
#include <stdint.h>

typedef int i32x4 __attribute__((ext_vector_type(4)));

__device__ __forceinline__ float blo(unsigned int u) {
  unsigned int v = u << 16; float f; __builtin_memcpy(&f, &v, 4); return f;
}
__device__ __forceinline__ float bhi(unsigned int u) {
  unsigned int v = u & 0xffff0000u; float f; __builtin_memcpy(&f, &v, 4); return f;
}
__device__ __forceinline__ int pack4q(float a, float b, float c, float d, float qm) {
  int i0 = (int)rintf(a * qm) & 255;
  int i1 = (int)rintf(b * qm) & 255;
  int i2 = (int)rintf(c * qm) & 255;
  int i3 = (int)rintf(d * qm) & 255;
  return i0 | (i1 << 8) | (i2 << 16) | (i3 << 24);
}

__device__ __forceinline__ float fast_gelu(float v) {
  // exact-erf GELU via Abramowitz-Stegun 7.1.26 (|erf err| <= 1.5e-7)
  float u = v * 0.70710678118654752f;
  float s = fabsf(u);
  float den = fmaf(0.3275911f, s, 1.0f);
  float t;
  asm("v_rcp_f32 %0, %1" : "=v"(t) : "v"(den));
  float p = t * fmaf(t, fmaf(t, fmaf(t, fmaf(t, 1.061405429f, -1.453152027f),
                                     1.421413741f), -0.284496736f), 0.254829592f);
  float e = fmaf(-p, __expf(-u * u), 1.0f);
  float er = copysignf(e, u);
  return 0.5f * v * (1.0f + er);
}

// ------------- weight absmean: both matrices in one dispatch (256 blocks each) -------------
__global__ void k_reduce_abs2(const float* __restrict__ w1, const float* __restrict__ w2,
                              long n4, float* __restrict__ partials) {
  const int half = gridDim.x >> 1;
  const float* w = (blockIdx.x < half) ? w1 : w2;
  int b = (blockIdx.x < half) ? blockIdx.x : blockIdx.x - half;
  const float4* wv = (const float4*)w;
  float s = 0.0f;
  long stride = (long)half * blockDim.x;
  for (long i = (long)b * blockDim.x + threadIdx.x; i < n4; i += stride) {
    float4 v = wv[i];
    s += fabsf(v.x) + fabsf(v.y) + fabsf(v.z) + fabsf(v.w);
  }
  #pragma unroll
  for (int off = 32; off; off >>= 1) s += __shfl_down(s, off);
  __shared__ float sw[4];
  if ((threadIdx.x & 63) == 0) sw[threadIdx.x >> 6] = s;
  __syncthreads();
  if (threadIdx.x == 0) partials[blockIdx.x] = sw[0] + sw[1] + sw[2] + sw[3];
}

// --- ternary weight quant -> i8 {-1,0,1}; scale computed inline from partials (256 each) ---
__global__ void k_quant_w2(const float* __restrict__ w1, char* __restrict__ wq1,
                           const float* __restrict__ w2, char* __restrict__ wq2,
                           long n4, const float* __restrict__ partials,
                           float* __restrict__ scales, float invW) {
  const int half = gridDim.x >> 1;
  const bool first = blockIdx.x < half;
  int t = threadIdx.x;  // 256 threads
  float p = partials[(first ? 0 : 256) + t];
  #pragma unroll
  for (int off = 32; off; off >>= 1) p += __shfl_down(p, off);
  __shared__ float a[4];
  if ((t & 63) == 0) a[t >> 6] = p;
  __syncthreads();
  float sc = fmaxf((a[0] + a[1] + a[2] + a[3]) * invW, 1e-5f);
  if (t == 0 && (blockIdx.x == 0 || blockIdx.x == half)) scales[first ? 0 : 1] = sc;
  float s = 1.0f / sc;
  const float* w = first ? w1 : w2;
  char* wq = first ? wq1 : wq2;
  int b = first ? blockIdx.x : blockIdx.x - half;
  const float4* wv = (const float4*)w;
  int* qv = (int*)wq;
  long stride = (long)half * blockDim.x;
  for (long i = (long)b * blockDim.x + t; i < n4; i += stride) {
    float4 v = wv[i];
    int b0 = (int)fminf(fmaxf(rintf(v.x * s), -1.0f), 1.0f) & 255;
    int b1 = (int)fminf(fmaxf(rintf(v.y * s), -1.0f), 1.0f) & 255;
    int b2 = (int)fminf(fmaxf(rintf(v.z * s), -1.0f), 1.0f) & 255;
    int b3 = (int)fminf(fmaxf(rintf(v.w * s), -1.0f), 1.0f) & 255;
    qv[i] = b0 | (b1 << 8) | (b2 << 16) | (b3 << 24);
  }
}

// ---------------- rmsnorm + per-token absmax int8 quant of x -> i8 (D=1024) ----------------
__global__ void k_actq_x(const float* __restrict__ x, char* __restrict__ xq,
                         float* __restrict__ alpha) {
  const int D = 1024;
  size_t t = blockIdx.x;
  int tid = threadIdx.x;
  const float4* row = (const float4*)(x + t * (size_t)D);
  float4 v = row[tid];
  float ss = v.x*v.x + v.y*v.y + v.z*v.z + v.w*v.w;
  float am = fmaxf(fmaxf(fabsf(v.x), fabsf(v.y)), fmaxf(fabsf(v.z), fabsf(v.w)));
  #pragma unroll
  for (int off = 32; off; off >>= 1) {
    ss += __shfl_down(ss, off);
    am = fmaxf(am, __shfl_down(am, off));
  }
  __shared__ float s_ss[4], s_am[4];
  if ((tid & 63) == 0) { s_ss[tid >> 6] = ss; s_am[tid >> 6] = am; }
  __syncthreads();
  ss = s_ss[0] + s_ss[1] + s_ss[2] + s_ss[3];
  am = fmaxf(fmaxf(s_am[0], s_am[1]), fmaxf(s_am[2], s_am[3]));
  float rms = rsqrtf(ss * (1.0f / D) + 1e-5f);
  float a   = fmaxf(am * rms, 1e-5f);
  float qs  = 127.0f / a;
  if (tid == 0) alpha[t] = a * (1.0f / 127.0f);
  int b0 = (int)fminf(fmaxf(rintf((v.x * rms) * qs), -128.0f), 127.0f) & 255;
  int b1 = (int)fminf(fmaxf(rintf((v.y * rms) * qs), -128.0f), 127.0f) & 255;
  int b2 = (int)fminf(fmaxf(rintf((v.z * rms) * qs), -128.0f), 127.0f) & 255;
  int b3 = (int)fminf(fmaxf(rintf((v.w * rms) * qs), -128.0f), 127.0f) & 255;
  ((int*)xq)[t * 256 + tid] = b0 | (b1 << 8) | (b2 << 16) | (b3 << 24);
}

// ------- rmsnorm + absmax quant of h (already gelu'd by GEMM1), IN PLACE -------
__global__ void k_actq_h(__hip_bfloat16* __restrict__ h, float* __restrict__ alpha) {
  const int F = 4096;
  size_t t = blockIdx.x;
  int tid = threadIdx.x;  // 256 threads * 16 elems
  char* rb = (char*)(h + t * (size_t)F);
  const uint4* row = (const uint4*)rb;
  uint4 u0 = row[tid], u1 = row[tid + 256];
  unsigned int uu[8] = {u0.x, u0.y, u0.z, u0.w, u1.x, u1.y, u1.z, u1.w};
  float ss = 0.0f, am = 0.0f;
  #pragma unroll
  for (int i = 0; i < 8; i++) {
    float f0 = blo(uu[i]), f1 = bhi(uu[i]);
    ss += f0 * f0 + f1 * f1;
    am = fmaxf(am, fmaxf(fabsf(f0), fabsf(f1)));
  }
  #pragma unroll
  for (int off = 32; off; off >>= 1) {
    ss += __shfl_down(ss, off);
    am = fmaxf(am, __shfl_down(am, off));
  }
  __shared__ float s_ss[4], s_am[4];
  if ((tid & 63) == 0) { s_ss[tid >> 6] = ss; s_am[tid >> 6] = am; }
  __syncthreads();   // also orders: all row reads complete before in-place writes
  ss = s_ss[0] + s_ss[1] + s_ss[2] + s_ss[3];
  am = fmaxf(fmaxf(s_am[0], s_am[1]), fmaxf(s_am[2], s_am[3]));
  float rms = rsqrtf(ss * (1.0f / F) + 1e-5f);
  float a   = fmaxf(am * rms, 1e-5f);
  float qm  = rms * (127.0f / a);
  if (tid == 0) alpha[t] = a * (1.0f / 127.0f);
  uint2 w0, w1;
  w0.x = (unsigned)pack4q(blo(uu[0]), bhi(uu[0]), blo(uu[1]), bhi(uu[1]), qm);
  w0.y = (unsigned)pack4q(blo(uu[2]), bhi(uu[2]), blo(uu[3]), bhi(uu[3]), qm);
  w1.x = (unsigned)pack4q(blo(uu[4]), bhi(uu[4]), blo(uu[5]), bhi(uu[5]), qm);
  w1.y = (unsigned)pack4q(blo(uu[6]), bhi(uu[6]), blo(uu[7]), bhi(uu[7]), qm);
  *(uint2*)(rb + 8 * tid) = w0;
  *(uint2*)(rb + 2048 + 8 * tid) = w1;
}

#define GLD16(GP, LP) __builtin_amdgcn_global_load_lds( \
    (__attribute__((address_space(1))) void*)(GP), \
    (__attribute__((address_space(3))) void*)(LP), 16, 0, 0)
#define VMCNT1 asm volatile("s_waitcnt vmcnt(1)" ::: "memory")
#define VMCNT0 asm volatile("s_waitcnt vmcnt(0)" ::: "memory")
#define LGKM0  do { asm volatile("s_waitcnt lgkmcnt(0)" ::: "memory"); __builtin_amdgcn_sched_barrier(0); } while(0)

// ====== FLAT-B i8 MFMA GEMM: 128x256 tile, 8 waves (2x4), wave tile 64x64 ======
// C[m,n] = sum_k A[m,k]*B[n,k], BK=64.  AITER-flatmm style: B (4 MB, L2-resident)
// is streamed DIRECTLY into registers per-lane (no LDS, no swizzle); only A goes
// through LDS (3 x 8 KB buffers, global_load_lds, both-sides XOR swizzle).  LDS
// read traffic per iter halves vs staged-B (4 ds_read/wave instead of 8).
// Ledger: per iter issue B(t+1)x4 then A(t+2)x1.  Top-of-loop FIFO (any intra-iter
// order) = {A(t), B(t)x4, A(t+1)} -> vmcnt(1) drains A(t)+B(t), leaves A(t+1).
// Compiler's dataflow waits additionally cover the bnext register loads.
// One barrier/iter (A visibility); buf[(t+2)%3] reuse is safe because every wave
// executed LGKM0 on its A(t-1) reads before reaching barrier(t).
template<int EPI>   // 0: gelu -> bf16 H    1: -> f32 Out
__global__ __launch_bounds__(512, 4) void k_gemm_flat(
    const char* __restrict__ A, int lda,          // A row stride in BYTES
    const char* __restrict__ B,                   // [N][K] i8, row stride K
    const float* __restrict__ bias, const float* __restrict__ alpha,
    const float* __restrict__ scales, int which,
    void* __restrict__ Cout, int N, int K, int lgnbx)
{
  __shared__ __align__(16) char lA[3 * 8192];    // [buf][128 rows][64 B]
  const int tid = threadIdx.x, lane = tid & 63, wid = tid >> 6;
  const int wm = wid >> 2, wn = wid & 3;
  const int nwg = gridDim.x, bid = blockIdx.x;
  const int swz = (bid & 7) * (nwg >> 3) + (bid >> 3);
  const int bx = swz & ((1 << lgnbx) - 1), by = swz >> lgnbx;
  const int m0 = by * 128, n0 = bx * 256;
  const int NT = K >> 6;

  // A staging: thread covers (srow, 16B slot); pre-swizzled global chunk
  const int srow = tid >> 2, slot = tid & 3;
  const int sswz = (slot ^ ((srow >> 1) & 3)) * 16;
  const char* gA = A + (size_t)(m0 + srow) * lda + sswz;
  const int ldst = srow * 64 + slot * 16;

  // A fragment reads (swizzled, conflict-free: verified 0 since R5)
  const int lr = lane & 15;
  const int kx = ((lane >> 4) ^ ((lane >> 1) & 3)) * 16;
  const int aoff = (wm * 64 + lr) * 64 + kx;

  // B direct per-lane: frag n covers rows n0+wn*64+n*16+lr, k-chunk lane>>4
  const char* gB = B + (size_t)(n0 + wn * 64 + lr) * K + (lane >> 4) * 16;
  const size_t bstep = (size_t)16 * K;

  // prologue: B(0) -> regs; A(0),A(1) -> LDS bufs 0,1
  i32x4 bcur[4], bnext[4];
  #pragma unroll
  for (int n = 0; n < 4; ++n) bnext[n] = *(const i32x4*)(gB + (size_t)n * bstep);
  GLD16(gA,      lA + ldst);
  GLD16(gA + 64, lA + 8192 + ldst);

  i32x4 acc[4][4] = {};
  int cur = 0, nx1 = 1, nx2 = 2;
  for (int t = 0; t < NT; ++t) {
    if (t + 1 < NT) { VMCNT1; } else { VMCNT0; }   // A(t) in LDS (own slice), B(t) landed
    #pragma unroll
    for (int n = 0; n < 4; ++n) bcur[n] = bnext[n];
    __builtin_amdgcn_s_barrier();                  // A(t) visible block-wide; buf[nx2] free
    if (t + 1 < NT) {
      const char* gb = gB + (size_t)(t + 1) * 64;
      #pragma unroll
      for (int n = 0; n < 4; ++n) bnext[n] = *(const i32x4*)(gb + (size_t)n * bstep);
    }
    if (t + 2 < NT) GLD16(gA + 64 * (t + 2), lA + nx2 * 8192 + ldst);
    const char* pa = lA + cur * 8192 + aoff;
    i32x4 av[4];
    #pragma unroll
    for (int j = 0; j < 4; ++j) av[j] = *(const i32x4*)(pa + j * 1024);
    LGKM0;
    __builtin_amdgcn_s_setprio(1);
    #pragma unroll
    for (int j = 0; j < 4; ++j)
      #pragma unroll
      for (int n = 0; n < 4; ++n)
        acc[j][n] = __builtin_amdgcn_mfma_i32_16x16x64_i8(av[j], bcur[n], acc[j][n], 0, 0, 0);
    __builtin_amdgcn_s_setprio(0);
    int tmp = cur; cur = nx1; nx1 = nx2; nx2 = tmp;
  }

  const float wdq = scales[which];
  const int lq4 = (lane >> 4) * 4;
  #pragma unroll
  for (int m = 0; m < 4; ++m) {
    const int rowb = m0 + wm * 64 + m * 16 + lq4;
    float al[4];
    #pragma unroll
    for (int q = 0; q < 4; ++q) al[q] = alpha[rowb + q] * wdq;
    #pragma unroll
    for (int n = 0; n < 4; ++n) {
      const int col = n0 + wn * 64 + n * 16 + lr;
      const float bb = bias[col];
      #pragma unroll
      for (int q = 0; q < 4; ++q) {
        float v = (float)acc[m][n][q] * al[q] + bb;
        if constexpr (EPI == 0) {
          ((__hip_bfloat16*)Cout)[(size_t)(rowb + q) * N + col] = __float2bfloat16(fast_gelu(v));
        } else {
          ((float*)Cout)[(size_t)(rowb + q) * N + col] = v;
        }
      }
    }
  }
}

extern "C" void kernel_launch(void* const* d_in, const int* in_sizes, int n_in,
                              void* d_out, int out_size, void* d_ws, size_t ws_size,
                              hipStream_t stream) {
  const float* x  = (const float*)d_in[0];
  const float* w1 = (const float*)d_in[1];
  const float* b1 = (const float*)d_in[2];
  const float* w2 = (const float*)d_in[3];
  const float* b2 = (const float*)d_in[4];
  const int  F = in_sizes[2];                 // 4096
  const int  D = in_sizes[4];                 // 1024
  const long T = (long)in_sizes[0] / D;       // 16384 tokens
  const long nW = (long)F * D;

  char* ws = (char*)d_ws;
  float* partials = (float*)ws;               // [512] (w1: 0..255, w2: 256..511)
  float* scales   = partials + 512;           // [2]
  float* alpha1 = (float*)(ws + 4096);        // [T]
  float* alpha2 = alpha1 + T;                 // [T]
  size_t off = 4096 + 2 * (size_t)T * sizeof(float);
  off = (off + 255) & ~(size_t)255;
  char* w1q = ws + off; off += (size_t)nW;
  char* w2q = ws + off; off += (size_t)nW;
  char* xq  = ws + off; off += (size_t)T * D;
  off = (off + 255) & ~(size_t)255;
  __hip_bfloat16* h = (__hip_bfloat16*)(ws + off); off += (size_t)T * F * 2;
  if (ws_size < off) return;

  float invW = (float)(1.0 / (double)nW);
  k_reduce_abs2<<<512, 256, 0, stream>>>(w1, w2, nW / 4, partials);
  k_quant_w2<<<4096, 256, 0, stream>>>(w1, w1q, w2, w2q, nW / 4, partials, scales, invW);
  k_actq_x<<<(unsigned)T, 256, 0, stream>>>(x, xq, alpha1);

  // GEMM1: [T x D] i8 @ [F x D]^T i8 -> gelu -> bf16 h   (flat-B, 128x256 tile)
  dim3 g1((unsigned)((T / 128) * (F / 256)));  // 2048 blocks
  k_gemm_flat<0><<<g1, 512, 0, stream>>>(xq, D, w1q, b1, alpha1, scales, 0,
                                         h, F, D, __builtin_ctz(F / 256));

  // rmsnorm + quant h in place (bf16 row -> leading i8 row, stride stays F*2 bytes)
  k_actq_h<<<(unsigned)T, 256, 0, stream>>>(h, alpha2);

  // GEMM2: [T x F] i8 (stride 2F) @ [D x F]^T i8 -> f32 out   (flat-B, 128x256 tile)
  dim3 g2((unsigned)((T / 128) * (D / 256)));  // 512 blocks
  k_gemm_flat<1><<<g2, 512, 0, stream>>>((const char*)h, F * 2, w2q, b2, alpha2, scales, 1,
                                         (float*)d_out, D, F, __builtin_ctz(D / 256));
}

// Round 14
// 242.856 us; speedup vs baseline: 1.5282x; 1.5282x over previous
//
#include <hip/hip_runtime.h>
#include <hip/hip_bf16.h>
#include <stdint.h>

typedef int i32x4 __attribute__((ext_vector_type(4)));

__device__ __forceinline__ float blo(unsigned int u) {
  unsigned int v = u << 16; float f; __builtin_memcpy(&f, &v, 4); return f;
}
__device__ __forceinline__ float bhi(unsigned int u) {
  unsigned int v = u & 0xffff0000u; float f; __builtin_memcpy(&f, &v, 4); return f;
}
__device__ __forceinline__ int pack4q(float a, float b, float c, float d, float qm) {
  int i0 = (int)rintf(a * qm) & 255;
  int i1 = (int)rintf(b * qm) & 255;
  int i2 = (int)rintf(c * qm) & 255;
  int i3 = (int)rintf(d * qm) & 255;
  return i0 | (i1 << 8) | (i2 << 16) | (i3 << 24);
}

__device__ __forceinline__ float fast_gelu(float v) {
  // exact-erf GELU via Abramowitz-Stegun 7.1.26 (|erf err| <= 1.5e-7)
  float u = v * 0.70710678118654752f;
  float s = fabsf(u);
  float den = fmaf(0.3275911f, s, 1.0f);
  float t;
  asm("v_rcp_f32 %0, %1" : "=v"(t) : "v"(den));
  float p = t * fmaf(t, fmaf(t, fmaf(t, fmaf(t, 1.061405429f, -1.453152027f),
                                     1.421413741f), -0.284496736f), 0.254829592f);
  float e = fmaf(-p, __expf(-u * u), 1.0f);
  float er = copysignf(e, u);
  return 0.5f * v * (1.0f + er);
}

// ------------- weight absmean: both matrices in one dispatch (256 blocks each) -------------
__global__ void k_reduce_abs2(const float* __restrict__ w1, const float* __restrict__ w2,
                              long n4, float* __restrict__ partials) {
  const int half = gridDim.x >> 1;
  const float* w = (blockIdx.x < half) ? w1 : w2;
  int b = (blockIdx.x < half) ? blockIdx.x : blockIdx.x - half;
  const float4* wv = (const float4*)w;
  float s = 0.0f;
  long stride = (long)half * blockDim.x;
  for (long i = (long)b * blockDim.x + threadIdx.x; i < n4; i += stride) {
    float4 v = wv[i];
    s += fabsf(v.x) + fabsf(v.y) + fabsf(v.z) + fabsf(v.w);
  }
  #pragma unroll
  for (int off = 32; off; off >>= 1) s += __shfl_down(s, off);
  __shared__ float sw[4];
  if ((threadIdx.x & 63) == 0) sw[threadIdx.x >> 6] = s;
  __syncthreads();
  if (threadIdx.x == 0) partials[blockIdx.x] = sw[0] + sw[1] + sw[2] + sw[3];
}

// --- ternary weight quant -> i8 {-1,0,1}, PACKED in MFMA-fragment order ---
// Packed layout: for nb = row/16, kb = k/64: 1KB block; lane = (row&15)|(((k>>4)&3)<<4);
// byte = k&15.  addr = ((nb*KB + kb)*64 + lane)*16 + byte.  A wave's B-fragment load
// is then one contiguous 1KB (16B/lane x 64 lanes) -> fully coalesced from L2.
__global__ void k_quant_w2(const float* __restrict__ w1, char* __restrict__ wq1,
                           const float* __restrict__ w2, char* __restrict__ wq2,
                           long n4, const float* __restrict__ partials,
                           float* __restrict__ scales, float invW,
                           int lgK1, int lgK2) {
  const int half = gridDim.x >> 1;
  const bool first = blockIdx.x < half;
  int t = threadIdx.x;  // 256 threads
  float p = partials[(first ? 0 : 256) + t];
  #pragma unroll
  for (int off = 32; off; off >>= 1) p += __shfl_down(p, off);
  __shared__ float a[4];
  if ((t & 63) == 0) a[t >> 6] = p;
  __syncthreads();
  float sc = fmaxf((a[0] + a[1] + a[2] + a[3]) * invW, 1e-5f);
  if (t == 0 && (blockIdx.x == 0 || blockIdx.x == half)) scales[first ? 0 : 1] = sc;
  float s = 1.0f / sc;
  const float* w = first ? w1 : w2;
  char* wq = first ? wq1 : wq2;
  const int lgK = first ? lgK1 : lgK2;
  const int K = 1 << lgK, KB = K >> 6;
  int b = first ? blockIdx.x : blockIdx.x - half;
  const float4* wv = (const float4*)w;
  int* qv = (int*)wq;
  long stride = (long)half * blockDim.x;
  for (long i = (long)b * blockDim.x + t; i < n4; i += stride) {
    float4 v = wv[i];
    int b0 = (int)fminf(fmaxf(rintf(v.x * s), -1.0f), 1.0f) & 255;
    int b1 = (int)fminf(fmaxf(rintf(v.y * s), -1.0f), 1.0f) & 255;
    int b2 = (int)fminf(fmaxf(rintf(v.z * s), -1.0f), 1.0f) & 255;
    int b3 = (int)fminf(fmaxf(rintf(v.w * s), -1.0f), 1.0f) & 255;
    long e = i << 2;                       // element index (4 consecutive k, same row)
    int row = (int)(e >> lgK);
    int k   = (int)(e & (long)(K - 1));
    int nb = row >> 4, kb = k >> 6;
    int lane = (row & 15) | (((k >> 4) & 3) << 4);
    long oidx = (((long)(nb * KB + kb)) << 8) + (lane << 2) + ((k & 15) >> 2);
    qv[oidx] = b0 | (b1 << 8) | (b2 << 16) | (b3 << 24);
  }
}

// ---------------- rmsnorm + per-token absmax int8 quant of x -> i8 (D=1024) ----------------
__global__ void k_actq_x(const float* __restrict__ x, char* __restrict__ xq,
                         float* __restrict__ alpha) {
  const int D = 1024;
  size_t t = blockIdx.x;
  int tid = threadIdx.x;
  const float4* row = (const float4*)(x + t * (size_t)D);
  float4 v = row[tid];
  float ss = v.x*v.x + v.y*v.y + v.z*v.z + v.w*v.w;
  float am = fmaxf(fmaxf(fabsf(v.x), fabsf(v.y)), fmaxf(fabsf(v.z), fabsf(v.w)));
  #pragma unroll
  for (int off = 32; off; off >>= 1) {
    ss += __shfl_down(ss, off);
    am = fmaxf(am, __shfl_down(am, off));
  }
  __shared__ float s_ss[4], s_am[4];
  if ((tid & 63) == 0) { s_ss[tid >> 6] = ss; s_am[tid >> 6] = am; }
  __syncthreads();
  ss = s_ss[0] + s_ss[1] + s_ss[2] + s_ss[3];
  am = fmaxf(fmaxf(s_am[0], s_am[1]), fmaxf(s_am[2], s_am[3]));
  float rms = rsqrtf(ss * (1.0f / D) + 1e-5f);
  float a   = fmaxf(am * rms, 1e-5f);
  float qs  = 127.0f / a;
  if (tid == 0) alpha[t] = a * (1.0f / 127.0f);
  int b0 = (int)fminf(fmaxf(rintf((v.x * rms) * qs), -128.0f), 127.0f) & 255;
  int b1 = (int)fminf(fmaxf(rintf((v.y * rms) * qs), -128.0f), 127.0f) & 255;
  int b2 = (int)fminf(fmaxf(rintf((v.z * rms) * qs), -128.0f), 127.0f) & 255;
  int b3 = (int)fminf(fmaxf(rintf((v.w * rms) * qs), -128.0f), 127.0f) & 255;
  ((int*)xq)[t * 256 + tid] = b0 | (b1 << 8) | (b2 << 16) | (b3 << 24);
}

// ------- rmsnorm + absmax quant of h (already gelu'd by GEMM1), IN PLACE -------
__global__ void k_actq_h(__hip_bfloat16* __restrict__ h, float* __restrict__ alpha) {
  const int F = 4096;
  size_t t = blockIdx.x;
  int tid = threadIdx.x;  // 256 threads * 16 elems
  char* rb = (char*)(h + t * (size_t)F);
  const uint4* row = (const uint4*)rb;
  uint4 u0 = row[tid], u1 = row[tid + 256];
  unsigned int uu[8] = {u0.x, u0.y, u0.z, u0.w, u1.x, u1.y, u1.z, u1.w};
  float ss = 0.0f, am = 0.0f;
  #pragma unroll
  for (int i = 0; i < 8; i++) {
    float f0 = blo(uu[i]), f1 = bhi(uu[i]);
    ss += f0 * f0 + f1 * f1;
    am = fmaxf(am, fmaxf(fabsf(f0), fabsf(f1)));
  }
  #pragma unroll
  for (int off = 32; off; off >>= 1) {
    ss += __shfl_down(ss, off);
    am = fmaxf(am, __shfl_down(am, off));
  }
  __shared__ float s_ss[4], s_am[4];
  if ((tid & 63) == 0) { s_ss[tid >> 6] = ss; s_am[tid >> 6] = am; }
  __syncthreads();   // also orders: all row reads complete before in-place writes
  ss = s_ss[0] + s_ss[1] + s_ss[2] + s_ss[3];
  am = fmaxf(fmaxf(s_am[0], s_am[1]), fmaxf(s_am[2], s_am[3]));
  float rms = rsqrtf(ss * (1.0f / F) + 1e-5f);
  float a   = fmaxf(am * rms, 1e-5f);
  float qm  = rms * (127.0f / a);
  if (tid == 0) alpha[t] = a * (1.0f / 127.0f);
  uint2 w0, w1;
  w0.x = (unsigned)pack4q(blo(uu[0]), bhi(uu[0]), blo(uu[1]), bhi(uu[1]), qm);
  w0.y = (unsigned)pack4q(blo(uu[2]), bhi(uu[2]), blo(uu[3]), bhi(uu[3]), qm);
  w1.x = (unsigned)pack4q(blo(uu[4]), bhi(uu[4]), blo(uu[5]), bhi(uu[5]), qm);
  w1.y = (unsigned)pack4q(blo(uu[6]), bhi(uu[6]), blo(uu[7]), bhi(uu[7]), qm);
  *(uint2*)(rb + 8 * tid) = w0;
  *(uint2*)(rb + 2048 + 8 * tid) = w1;
}

#define GLD16(GP, LP) __builtin_amdgcn_global_load_lds( \
    (__attribute__((address_space(1))) void*)(GP), \
    (__attribute__((address_space(3))) void*)(LP), 16, 0, 0)
#define VMCNT1 asm volatile("s_waitcnt vmcnt(1)" ::: "memory")
#define VMCNT0 asm volatile("s_waitcnt vmcnt(0)" ::: "memory")
#define LGKM0  do { asm volatile("s_waitcnt lgkmcnt(0)" ::: "memory"); __builtin_amdgcn_sched_barrier(0); } while(0)

// ====== PACKED-FLAT-B i8 MFMA GEMM: 128x256 tile, 8 waves (2x4), wave tile 64x64 ======
// B is pre-packed in fragment-major 1KB blocks (see k_quant_w2): a wave's B-frag load
// is one coalesced 1KB dwordx4.  B never touches LDS; A staged via global_load_lds
// into 3 x 8KB buffers with the proven both-sides XOR swizzle (0 conflicts).
// Ledger: per iter issue B(t+1)x4 then A(t+2)x1.  Top-of-loop FIFO = {A(t), B(t)x4,
// A(t+1)} -> vmcnt(1) drains A(t)+B(t), leaves A(t+1).  One barrier/iter.
template<int EPI>   // 0: gelu -> bf16 H    1: -> f32 Out
__global__ __launch_bounds__(512, 4) void k_gemm_flat(
    const char* __restrict__ A, int lda,          // A row stride in BYTES
    const char* __restrict__ B,                   // packed fragment-major (KB = K/64)
    const float* __restrict__ bias, const float* __restrict__ alpha,
    const float* __restrict__ scales, int which,
    void* __restrict__ Cout, int N, int K, int lgnbx)
{
  __shared__ __align__(16) char lA[3 * 8192];    // [buf][128 rows][64 B]
  const int tid = threadIdx.x, lane = tid & 63, wid = tid >> 6;
  const int wm = wid >> 2, wn = wid & 3;
  const int nwg = gridDim.x, bid = blockIdx.x;
  const int swz = (bid & 7) * (nwg >> 3) + (bid >> 3);
  const int bx = swz & ((1 << lgnbx) - 1), by = swz >> lgnbx;
  const int m0 = by * 128, n0 = bx * 256;
  const int NT = K >> 6, KB = K >> 6;

  // A staging: thread covers (srow, 16B slot); pre-swizzled global chunk
  const int srow = tid >> 2, slot = tid & 3;
  const int sswz = (slot ^ ((srow >> 1) & 3)) * 16;
  const char* gA = A + (size_t)(m0 + srow) * lda + sswz;
  const int ldst = srow * 64 + slot * 16;

  // A fragment reads (swizzled, conflict-free: verified 0 since R5)
  const int lr = lane & 15;
  const int kx = ((lane >> 4) ^ ((lane >> 1) & 3)) * 16;
  const int aoff = (wm * 64 + lr) * 64 + kx;

  // B packed: frag n, k-tile t at  ((n0/16 + wn*4 + n)*KB + t)*1024 + lane*16
  const char* gB = B + ((size_t)((n0 >> 4) + wn * 4) * KB) * 1024 + lane * 16;
  const size_t bstep = (size_t)KB * 1024;

  // prologue: B(0) -> regs; A(0),A(1) -> LDS bufs 0,1
  i32x4 bcur[4], bnext[4];
  #pragma unroll
  for (int n = 0; n < 4; ++n) bnext[n] = *(const i32x4*)(gB + (size_t)n * bstep);
  GLD16(gA,      lA + ldst);
  GLD16(gA + 64, lA + 8192 + ldst);

  i32x4 acc[4][4] = {};
  int cur = 0, nx1 = 1, nx2 = 2;
  for (int t = 0; t < NT; ++t) {
    if (t + 1 < NT) { VMCNT1; } else { VMCNT0; }   // A(t) in LDS (own slice), B(t) landed
    #pragma unroll
    for (int n = 0; n < 4; ++n) bcur[n] = bnext[n];
    __builtin_amdgcn_s_barrier();                  // A(t) visible block-wide; buf[nx2] free
    if (t + 1 < NT) {
      const char* gb = gB + (size_t)(t + 1) * 1024;
      #pragma unroll
      for (int n = 0; n < 4; ++n) bnext[n] = *(const i32x4*)(gb + (size_t)n * bstep);
    }
    if (t + 2 < NT) GLD16(gA + 64 * (t + 2), lA + nx2 * 8192 + ldst);
    const char* pa = lA + cur * 8192 + aoff;
    i32x4 av[4];
    #pragma unroll
    for (int j = 0; j < 4; ++j) av[j] = *(const i32x4*)(pa + j * 1024);
    LGKM0;
    __builtin_amdgcn_s_setprio(1);
    #pragma unroll
    for (int j = 0; j < 4; ++j)
      #pragma unroll
      for (int n = 0; n < 4; ++n)
        acc[j][n] = __builtin_amdgcn_mfma_i32_16x16x64_i8(av[j], bcur[n], acc[j][n], 0, 0, 0);
    __builtin_amdgcn_s_setprio(0);
    int tmp = cur; cur = nx1; nx1 = nx2; nx2 = tmp;
  }

  const float wdq = scales[which];
  const int lq4 = (lane >> 4) * 4;
  #pragma unroll
  for (int m = 0; m < 4; ++m) {
    const int rowb = m0 + wm * 64 + m * 16 + lq4;
    float al[4];
    #pragma unroll
    for (int q = 0; q < 4; ++q) al[q] = alpha[rowb + q] * wdq;
    #pragma unroll
    for (int n = 0; n < 4; ++n) {
      const int col = n0 + wn * 64 + n * 16 + lr;
      const float bb = bias[col];
      #pragma unroll
      for (int q = 0; q < 4; ++q) {
        float v = (float)acc[m][n][q] * al[q] + bb;
        if constexpr (EPI == 0) {
          ((__hip_bfloat16*)Cout)[(size_t)(rowb + q) * N + col] = __float2bfloat16(fast_gelu(v));
        } else {
          ((float*)Cout)[(size_t)(rowb + q) * N + col] = v;
        }
      }
    }
  }
}

extern "C" void kernel_launch(void* const* d_in, const int* in_sizes, int n_in,
                              void* d_out, int out_size, void* d_ws, size_t ws_size,
                              hipStream_t stream) {
  const float* x  = (const float*)d_in[0];
  const float* w1 = (const float*)d_in[1];
  const float* b1 = (const float*)d_in[2];
  const float* w2 = (const float*)d_in[3];
  const float* b2 = (const float*)d_in[4];
  const int  F = in_sizes[2];                 // 4096
  const int  D = in_sizes[4];                 // 1024
  const long T = (long)in_sizes[0] / D;       // 16384 tokens
  const long nW = (long)F * D;

  char* ws = (char*)d_ws;
  float* partials = (float*)ws;               // [512] (w1: 0..255, w2: 256..511)
  float* scales   = partials + 512;           // [2]
  float* alpha1 = (float*)(ws + 4096);        // [T]
  float* alpha2 = alpha1 + T;                 // [T]
  size_t off = 4096 + 2 * (size_t)T * sizeof(float);
  off = (off + 255) & ~(size_t)255;
  char* w1q = ws + off; off += (size_t)nW;
  char* w2q = ws + off; off += (size_t)nW;
  char* xq  = ws + off; off += (size_t)T * D;
  off = (off + 255) & ~(size_t)255;
  __hip_bfloat16* h = (__hip_bfloat16*)(ws + off); off += (size_t)T * F * 2;
  if (ws_size < off) return;

  float invW = (float)(1.0 / (double)nW);
  k_reduce_abs2<<<512, 256, 0, stream>>>(w1, w2, nW / 4, partials);
  k_quant_w2<<<4096, 256, 0, stream>>>(w1, w1q, w2, w2q, nW / 4, partials, scales, invW,
                                       __builtin_ctz(D), __builtin_ctz(F));
  k_actq_x<<<(unsigned)T, 256, 0, stream>>>(x, xq, alpha1);

  // GEMM1: [T x D] i8 @ packed w1q -> gelu -> bf16 h   (packed-flat-B, 128x256 tile)
  dim3 g1((unsigned)((T / 128) * (F / 256)));  // 2048 blocks
  k_gemm_flat<0><<<g1, 512, 0, stream>>>(xq, D, w1q, b1, alpha1, scales, 0,
                                         h, F, D, __builtin_ctz(F / 256));

  // rmsnorm + quant h in place (bf16 row -> leading i8 row, stride stays F*2 bytes)
  k_actq_h<<<(unsigned)T, 256, 0, stream>>>(h, alpha2);

  // GEMM2: [T x F] i8 (stride 2F) @ packed w2q -> f32 out   (packed-flat-B)
  dim3 g2((unsigned)((T / 128) * (D / 256)));  // 512 blocks
  k_gemm_flat<1><<<g2, 512, 0, stream>>>((const char*)h, F * 2, w2q, b2, alpha2, scales, 1,
                                         (float*)d_out, D, F, __builtin_ctz(D / 256));
}